// Round 11
// baseline (261.041 us; speedup 1.0000x reference)
//
#include <hip/hip_runtime.h>
#include <hip/hip_bf16.h>

typedef unsigned short u16;
typedef __attribute__((ext_vector_type(8))) short bf16x8;
typedef __attribute__((ext_vector_type(4))) float f32x4;

__device__ __forceinline__ u16 f2bf(float f) {
  union { float f; unsigned u; } a;
  a.f = f;
  unsigned r = (a.u + 0x7FFFu + ((a.u >> 16) & 1u)) >> 16;  // RN-even
  return (u16)r;
}

// ---------------------------------------------------------------------------
// Prep: fp32 -> bf16 copies of x and y, plus per-row sum of squares.
// ---------------------------------------------------------------------------
__global__ __launch_bounds__(128) void rbf_prep(
    const float* __restrict__ x, const float* __restrict__ y,
    u16* __restrict__ xb, u16* __restrict__ yb,
    float* __restrict__ xsq, float* __restrict__ ysq,
    int N, int M, int D) {
  int row = blockIdx.x;
  const float* src;
  u16* dst;
  float* sq;
  if (row < N) {
    src = x + (size_t)row * D;
    dst = xb + (size_t)row * D;
    sq = xsq + row;
  } else {
    int r = row - N;
    src = y + (size_t)r * D;
    dst = yb + (size_t)r * D;
    sq = ysq + r;
  }
  int t = threadIdx.x;
  float4 v = reinterpret_cast<const float4*>(src)[t];
  float s = v.x * v.x + v.y * v.y + v.z * v.z + v.w * v.w;
  ushort4 o;
  o.x = f2bf(v.x);
  o.y = f2bf(v.y);
  o.z = f2bf(v.z);
  o.w = f2bf(v.w);
  reinterpret_cast<ushort4*>(dst)[t] = o;
  #pragma unroll
  for (int off = 32; off > 0; off >>= 1) s += __shfl_down(s, off, 64);
  __shared__ float red[2];
  if ((t & 63) == 0) red[t >> 6] = s;
  __syncthreads();
  if (t == 0) sq[0] = red[0] + red[1];
}

// ---------------------------------------------------------------------------
// R11: ZERO-BARRIER, ZERO-LDS streaming GEMM.
// Every wave independently owns a 64x64 output tile; 4 waves per block with
// NO __syncthreads anywhere. Operand fragments load DIRECT from global
// (L2-resident bf16 panels; one wave-load = 16 rows x 64 B dense segments,
// adjacent K-steps share 128B lines -> L1 hits). Manual even/odd register
// double-buffer (named sets, static indices, no asm): load set B for step
// k+1, MFMA with set A for step k, load set A for k+2, MFMA set B --
// compiler emits counted vmcnt at first use = software pipeline without
// barriers. ~150-170 VGPR -> 3 blocks/CU = 12 independent wave-pipelines
// per CU; a stall in one wave never convoys the others.
// Rationale: 10 rounds of evidence show the barrier-locked LDS K-loop
// plateaus at GEMM 104-124 us with ALL pipes <30% busy -- the convoy is
// the invariant, so remove it.
// Swapped MFMA operands: D[j][i] -> per-thread 4 consecutive out columns ->
// float4 stores. Column-band supertile on 128x128 regions for L2.
// exp2-fused epilogue.
// ---------------------------------------------------------------------------
__global__ __launch_bounds__(256, 3) void rbf_gemm(
    const u16* __restrict__ xb, const u16* __restrict__ yb,
    const float* __restrict__ xsq, const float* __restrict__ ysq,
    const float* __restrict__ gptr, float* __restrict__ out,
    int N, int M, int D) {
  int bid = blockIdx.x;
  int nbr = N / 128, nbc = M / 128;
  int trow, tcol;
  if (nbr == 64 && nbc == 64) {
    // XCD x owns region-columns x*8..x*8+7, walked in 8x8-region chunks
    // (column-major inside): panels stay L2-resident per XCD.
    int xcd = bid & 7;
    int s = bid >> 3;        // 0..511
    int gr = s >> 6;         // chunk row 0..7
    int q = s & 63;          // within-chunk, column-major
    trow = gr * 8 + (q & 7);
    tcol = xcd * 8 + (q >> 3);
  } else {
    int cpx = gridDim.x >> 3;
    int swz = (bid & 7) * cpx + (bid >> 3);
    trow = swz / nbc;
    tcol = swz % nbc;
  }

  int tid = threadIdx.x;
  int w = tid >> 6;       // wave 0..3 (independent tiles, never synced)
  int lane = tid & 63;
  int wm = w >> 1;        // 0..1 : x 64-row half within the 128x128 region
  int wn = w & 1;         // 0..1 : y 64-row half
  int fr = lane & 15;
  int fq = lane >> 4;

  int brow = trow * 128 + wm * 64;   // this wave's x rows (out rows i)
  int bcol = tcol * 128 + wn * 64;   // this wave's y rows (out cols j)

  const u16* xrow = xb + (size_t)(brow + fr) * D + fq * 8;
  const u16* yrow = yb + (size_t)(bcol + fr) * D + fq * 8;
  const size_t rstep = (size_t)16 * D;  // 16 rows

  f32x4 acc[4][4];
  #pragma unroll
  for (int m = 0; m < 4; ++m)
    #pragma unroll
    for (int n = 0; n < 4; ++n)
      acc[m][n] = (f32x4){0.f, 0.f, 0.f, 0.f};

  bf16x8 afA[4], bfA[4], afB[4], bfB[4];

  // prologue: K-step 0 into set A
  #pragma unroll
  for (int m = 0; m < 4; ++m) afA[m] = *(const bf16x8*)&xrow[m * rstep];
  #pragma unroll
  for (int n = 0; n < 4; ++n) bfA[n] = *(const bf16x8*)&yrow[n * rstep];

  int NK = D >> 5;  // K-steps of 32 (even; guarded in launcher)
  #pragma unroll 2
  for (int k = 0; k < NK; k += 2) {
    // load step k+1 into set B
    int k1 = (k + 1) << 5;
    #pragma unroll
    for (int m = 0; m < 4; ++m) afB[m] = *(const bf16x8*)&xrow[m * rstep + k1];
    #pragma unroll
    for (int n = 0; n < 4; ++n) bfB[n] = *(const bf16x8*)&yrow[n * rstep + k1];
    // MFMA step k with set A (swapped: D[j][i])
    #pragma unroll
    for (int m = 0; m < 4; ++m)
      #pragma unroll
      for (int n = 0; n < 4; ++n)
        acc[m][n] = __builtin_amdgcn_mfma_f32_16x16x32_bf16(
            bfA[n], afA[m], acc[m][n], 0, 0, 0);
    // load step k+2 into set A
    if (k + 2 < NK) {
      int k2 = (k + 2) << 5;
      #pragma unroll
      for (int m = 0; m < 4; ++m)
        afA[m] = *(const bf16x8*)&xrow[m * rstep + k2];
      #pragma unroll
      for (int n = 0; n < 4; ++n)
        bfA[n] = *(const bf16x8*)&yrow[n * rstep + k2];
    }
    // MFMA step k+1 with set B
    #pragma unroll
    for (int m = 0; m < 4; ++m)
      #pragma unroll
      for (int n = 0; n < 4; ++n)
        acc[m][n] = __builtin_amdgcn_mfma_f32_16x16x32_bf16(
            bfB[n], afB[m], acc[m][n], 0, 0, 0);
  }

  // Epilogue: out = exp2(2*gl2*acc - gl2*|x|^2 - gl2*|y|^2), clamped <= 2^0.
  // Layout: i = brow + m*16 + fr (row), j = bcol + n*16 + fq*4 + r (col).
  float gl2 = gptr[0] * 1.44269504088896f;  // gamma * log2(e)
  float m2gl2 = 2.0f * gl2;
  float4 gys[4];
  #pragma unroll
  for (int n = 0; n < 4; ++n) {
    float4 t4 = *reinterpret_cast<const float4*>(&ysq[bcol + n * 16 + fq * 4]);
    gys[n].x = gl2 * t4.x;
    gys[n].y = gl2 * t4.y;
    gys[n].z = gl2 * t4.z;
    gys[n].w = gl2 * t4.w;
  }
  #pragma unroll
  for (int m = 0; m < 4; ++m) {
    int i = brow + m * 16 + fr;
    float gxs = gl2 * xsq[i];
    size_t ro = (size_t)i * M;
    #pragma unroll
    for (int n = 0; n < 4; ++n) {
      int jb = bcol + n * 16 + fq * 4;
      float4 e;
      e.x = exp2f(fminf(fmaf(m2gl2, acc[m][n][0], -(gxs + gys[n].x)), 0.f));
      e.y = exp2f(fminf(fmaf(m2gl2, acc[m][n][1], -(gxs + gys[n].y)), 0.f));
      e.z = exp2f(fminf(fmaf(m2gl2, acc[m][n][2], -(gxs + gys[n].z)), 0.f));
      e.w = exp2f(fminf(fmaf(m2gl2, acc[m][n][3], -(gxs + gys[n].w)), 0.f));
      *reinterpret_cast<float4*>(&out[ro + jb]) = e;
    }
  }
}

// ---------------------------------------------------------------------------
// Fallback: fp32 LDS-tiled, slow but correct for odd shapes.
// ---------------------------------------------------------------------------
__global__ __launch_bounds__(256) void rbf_naive(
    const float* __restrict__ x, const float* __restrict__ y,
    const float* __restrict__ gptr, float* __restrict__ out,
    int N, int M, int D) {
  __shared__ float xs[16][17];
  __shared__ float ys[16][17];
  int nbn = M / 16;
  int brow = (blockIdx.x / nbn) * 16;
  int bcol = (blockIdx.x % nbn) * 16;
  int ti = threadIdx.x >> 4, tj = threadIdx.x & 15;
  float dacc = 0.f, xacc = 0.f, yacc = 0.f;
  for (int k0 = 0; k0 < D; k0 += 16) {
    xs[ti][tj] = x[(size_t)(brow + ti) * D + k0 + tj];
    ys[ti][tj] = y[(size_t)(bcol + ti) * D + k0 + tj];
    __syncthreads();
    #pragma unroll
    for (int kk = 0; kk < 16; ++kk) {
      float xv = xs[ti][kk], yv = ys[tj][kk];
      dacc += xv * yv;
      xacc += xv * xv;
      yacc += yv * yv;
    }
    __syncthreads();
  }
  float gamma = gptr[0];
  float d2 = fmaxf(xacc + yacc - 2.f * dacc, 0.f);
  out[(size_t)(brow + ti) * M + (bcol + tj)] = __expf(-gamma * d2);
}

// ---------------------------------------------------------------------------
extern "C" void kernel_launch(void* const* d_in, const int* in_sizes, int n_in,
                              void* d_out, int out_size, void* d_ws,
                              size_t ws_size, hipStream_t stream) {
  const float* x = (const float*)d_in[0];
  const float* y = (const float*)d_in[1];
  const float* g = (const float*)d_in[2];
  float* out = (float*)d_out;

  const int D = 512;
  const int N = in_sizes[0] / D;
  const int M = in_sizes[1] / D;

  size_t need = (size_t)(N + M) * D * sizeof(u16) + (size_t)(N + M) * sizeof(float);
  bool shapes_ok = (N % 128 == 0) && (M % 128 == 0) && (D % 64 == 0);

  if (ws_size >= need && shapes_ok) {
    u16* xb = (u16*)d_ws;
    u16* yb = xb + (size_t)N * D;
    float* xsq = (float*)(yb + (size_t)M * D);
    float* ysq = xsq + N;

    rbf_prep<<<N + M, 128, 0, stream>>>(x, y, xb, yb, xsq, ysq, N, M, D);
    int nwg = (N / 128) * (M / 128);
    rbf_gemm<<<nwg, 256, 0, stream>>>(xb, yb, xsq, ysq, g, out, N, M, D);
  } else {
    rbf_naive<<<(N / 16) * (M / 16), 256, 0, stream>>>(x, y, g, out, N, M, D);
  }
}

// Round 12
// 117.291 us; speedup vs baseline: 2.2256x; 2.2256x over previous
//
#include <hip/hip_runtime.h>
#include <hip/hip_bf16.h>

typedef unsigned short u16;
typedef __attribute__((ext_vector_type(8))) short bf16x8;
typedef __attribute__((ext_vector_type(4))) float f32x4;

typedef const __attribute__((address_space(1))) void gvoid_t;
typedef __attribute__((address_space(3))) void lvoid_t;

__device__ __forceinline__ void gload_lds16(const void* g, void* l) {
  __builtin_amdgcn_global_load_lds((gvoid_t*)g, (lvoid_t*)l, 16, 0, 0);
}

__device__ __forceinline__ u16 f2bf(float f) {
  union { float f; unsigned u; } a;
  a.f = f;
  unsigned r = (a.u + 0x7FFFu + ((a.u >> 16) & 1u)) >> 16;  // RN-even
  return (u16)r;
}

// ---------------------------------------------------------------------------
// Prep: fp32 -> bf16 copies of x and y, plus per-row sum of squares.
// ---------------------------------------------------------------------------
__global__ __launch_bounds__(128) void rbf_prep(
    const float* __restrict__ x, const float* __restrict__ y,
    u16* __restrict__ xb, u16* __restrict__ yb,
    float* __restrict__ xsq, float* __restrict__ ysq,
    int N, int M, int D) {
  int row = blockIdx.x;
  const float* src;
  u16* dst;
  float* sq;
  if (row < N) {
    src = x + (size_t)row * D;
    dst = xb + (size_t)row * D;
    sq = xsq + row;
  } else {
    int r = row - N;
    src = y + (size_t)r * D;
    dst = yb + (size_t)r * D;
    sq = ysq + r;
  }
  int t = threadIdx.x;
  float4 v = reinterpret_cast<const float4*>(src)[t];
  float s = v.x * v.x + v.y * v.y + v.z * v.z + v.w * v.w;
  ushort4 o;
  o.x = f2bf(v.x);
  o.y = f2bf(v.y);
  o.z = f2bf(v.z);
  o.w = f2bf(v.w);
  reinterpret_cast<ushort4*>(dst)[t] = o;
  #pragma unroll
  for (int off = 32; off > 0; off >>= 1) s += __shfl_down(s, off, 64);
  __shared__ float red[2];
  if ((t & 63) == 0) red[t >> 6] = s;
  __syncthreads();
  if (t == 0) sq[0] = red[0] + red[1];
}

// ---------------------------------------------------------------------------
// R12 = R5 base + 4-OUTPUT-TILE CONSOLIDATION per block.
// Block owns one 128-row x-panel and 4 adjacent 128-col y-tiles; runs ONE
// seamless 32-step pipeline (step s: kt=s&7, tile bt=s>>3) with the R5
// cadence (LDS 64 KiB dbuf, 3-bit chunk^=(row&7) swizzle both sides,
// counted vmcnt(8), 2 barriers/step, setprio MFMA). Tile epilogues are
// issued between ds_reads and MFMAs of the following step -- exp VALU and
// stores overlap in-flight LDS reads; stores are fire-and-forget and all
// waits remain conservative vmcnt(8) (no store-retirement-order assumption).
// Removes 3/4 of per-block warmup/drain; x-panel staging for tiles 1-3 is
// L2-hot. Swapped MFMA operands -> D[j][i] -> float4 out stores.
// ---------------------------------------------------------------------------
#define BM 128
#define BN 128
#define BK 64
#define NTILE 4

__global__ __launch_bounds__(256, 2) void rbf_gemm(
    const u16* __restrict__ xb, const u16* __restrict__ yb,
    const float* __restrict__ xsq, const float* __restrict__ ysq,
    const float* __restrict__ gptr, float* __restrict__ out,
    int N, int M, int D) {
  __shared__ u16 lds[2][2][BM * BK];  // 64 KiB

  int bid = blockIdx.x;
  int nbr = N / BM;          // row tiles
  int ncg = M / (BN * NTILE);  // column groups of 4 tiles
  int trow, cg;
  if (nbr == 64 && ncg == 16) {
    // XCD x owns col-groups {2x, 2x+1}; within: 8-row chunks, column-major.
    int xcd = bid & 7;
    int s = bid >> 3;            // 0..127
    trow = (s >> 4) * 8 + (s & 7);
    cg = xcd * 2 + ((s >> 3) & 1);
  } else {
    int cpx = gridDim.x >> 3;
    int swz = (bid & 7) * cpx + (bid >> 3);
    trow = swz / ncg;
    cg = swz % ncg;
  }
  int brow = trow * BM;
  int bcol0 = cg * (BN * NTILE);

  int tid = threadIdx.x;
  int w = tid >> 6;       // wave 0..3
  int lane = tid & 63;
  int wm = w >> 1;        // 0..1 row half (64 rows)
  int wn = w & 1;         // 0..1 col half (64 cols)
  int fr = lane & 15;
  int fq = lane >> 4;

  // --- staging: wave w stages rows w*32..w*32+31 of A and B tiles ---
  int srow = lane >> 3;                        // 0..7
  int scol = ((lane & 7) ^ srow) * 8;          // inverse-swizzled source col
  const u16* xsrc = xb + (size_t)(brow + w * 32 + srow) * D + scol;
  const u16* ysrc0 = yb + (size_t)(bcol0 + w * 32 + srow) * D + scol;
  int sdst = w * 2048;  // 32 rows * 64 elems

  // --- fragment read offsets: chunk ^= (row&7) ---
  int cxor = (fr & 7) * 8;
  int colx0 = (fq * 8) ^ cxor;        // kk=0
  int colx1 = (32 + fq * 8) ^ cxor;   // kk=1
  int arow0 = (wm * 64 + fr) * 64;
  int brow0 = (wn * 64 + fr) * 64;

  float gl2 = gptr[0] * 1.44269504088896f;  // gamma * log2(e)
  float m2gl2 = 2.0f * gl2;

  f32x4 acc[4][4];
  #pragma unroll
  for (int m = 0; m < 4; ++m)
    #pragma unroll
    for (int n = 0; n < 4; ++n)
      acc[m][n] = (f32x4){0.f, 0.f, 0.f, 0.f};

  // stage step s: kt = s&7 (K column), bt = s>>3 (output tile)
  auto stage = [&](int s) {
    int kt = s & 7;
    int bt = s >> 3;
    int b = s & 1;
    const u16* xs = xsrc + kt * 64;
    const u16* ys = ysrc0 + (size_t)bt * BN * D + kt * 64;
    u16* la = &lds[b][0][sdst];
    u16* lb = &lds[b][1][sdst];
    #pragma unroll
    for (int i = 0; i < 4; ++i)
      gload_lds16(xs + (size_t)i * 8 * D, la + i * 512);
    #pragma unroll
    for (int i = 0; i < 4; ++i)
      gload_lds16(ys + (size_t)i * 8 * D, lb + i * 512);
  };

  // epilogue for finished tile bt: exp + float4 stores, then zero acc.
  auto epilogue = [&](int bt) {
    int bcol = bcol0 + bt * BN;
    #pragma unroll
    for (int m = 0; m < 4; ++m) {
      int i = brow + wm * 64 + m * 16 + fr;
      float gxs = gl2 * xsq[i];
      size_t ro = (size_t)i * M;
      #pragma unroll
      for (int n = 0; n < 4; ++n) {
        int jb = bcol + wn * 64 + n * 16 + fq * 4;
        float4 ys4 = *reinterpret_cast<const float4*>(&ysq[jb]);
        float4 e;
        e.x = exp2f(fminf(fmaf(m2gl2, acc[m][n][0], -fmaf(gl2, ys4.x, gxs)), 0.f));
        e.y = exp2f(fminf(fmaf(m2gl2, acc[m][n][1], -fmaf(gl2, ys4.y, gxs)), 0.f));
        e.z = exp2f(fminf(fmaf(m2gl2, acc[m][n][2], -fmaf(gl2, ys4.z, gxs)), 0.f));
        e.w = exp2f(fminf(fmaf(m2gl2, acc[m][n][3], -fmaf(gl2, ys4.w, gxs)), 0.f));
        *reinterpret_cast<float4*>(&out[ro + jb]) = e;
      }
    }
    #pragma unroll
    for (int m = 0; m < 4; ++m)
      #pragma unroll
      for (int n = 0; n < 4; ++n)
        acc[m][n] = (f32x4){0.f, 0.f, 0.f, 0.f};
  };

  const int NS = (D >> 6) * NTILE;  // 32 steps for D=512
  stage(0);
  stage(1);
  for (int s = 0; s < NS; ++s) {
    int b = s & 1;
    // stage(s)'s 8 loads landed; stage(s+1)'s 8 stay in flight.
    // (conservative: also waits on any not-yet-retired epilogue stores)
    if (s + 1 < NS)
      asm volatile("s_waitcnt vmcnt(8)" ::: "memory");
    else
      asm volatile("s_waitcnt vmcnt(0)" ::: "memory");
    __builtin_amdgcn_sched_barrier(0);
    __builtin_amdgcn_s_barrier();  // all waves' step-s data visible
    __builtin_amdgcn_sched_barrier(0);

    const u16* A = &lds[b][0][0];
    const u16* B = &lds[b][1][0];
    bf16x8 af[4][2], bf[4][2];
    #pragma unroll
    for (int m = 0; m < 4; ++m) {
      af[m][0] = *(const bf16x8*)&A[arow0 + m * 1024 + colx0];
      af[m][1] = *(const bf16x8*)&A[arow0 + m * 1024 + colx1];
    }
    #pragma unroll
    for (int n = 0; n < 4; ++n) {
      bf[n][0] = *(const bf16x8*)&B[brow0 + n * 1024 + colx0];
      bf[n][1] = *(const bf16x8*)&B[brow0 + n * 1024 + colx1];
    }

    // finished-tile epilogue overlaps the in-flight ds_reads above
    if (s >= 8 && (s & 7) == 0) epilogue((s >> 3) - 1);

    asm volatile("s_waitcnt lgkmcnt(0)" ::: "memory");
    __builtin_amdgcn_sched_barrier(0);
    // Swapped operands: D[j][i], j = fq*4 + r, i = fr.
    __builtin_amdgcn_s_setprio(1);
    #pragma unroll
    for (int m = 0; m < 4; ++m)
      #pragma unroll
      for (int n = 0; n < 4; ++n) {
        acc[m][n] = __builtin_amdgcn_mfma_f32_16x16x32_bf16(
            bf[n][0], af[m][0], acc[m][n], 0, 0, 0);
        acc[m][n] = __builtin_amdgcn_mfma_f32_16x16x32_bf16(
            bf[n][1], af[m][1], acc[m][n], 0, 0, 0);
      }
    __builtin_amdgcn_s_setprio(0);

    __builtin_amdgcn_sched_barrier(0);
    __builtin_amdgcn_s_barrier();  // all reads of buf b retired (lgkm above)
    __builtin_amdgcn_sched_barrier(0);
    if (s + 2 < NS) stage(s + 2);
  }
  epilogue(NTILE - 1);
}

// ---------------------------------------------------------------------------
// Fallback: fp32 LDS-tiled, slow but correct for odd shapes.
// ---------------------------------------------------------------------------
__global__ __launch_bounds__(256) void rbf_naive(
    const float* __restrict__ x, const float* __restrict__ y,
    const float* __restrict__ gptr, float* __restrict__ out,
    int N, int M, int D) {
  __shared__ float xs[16][17];
  __shared__ float ys[16][17];
  int nbn = M / 16;
  int brow = (blockIdx.x / nbn) * 16;
  int bcol = (blockIdx.x % nbn) * 16;
  int ti = threadIdx.x >> 4, tj = threadIdx.x & 15;
  float dacc = 0.f, xacc = 0.f, yacc = 0.f;
  for (int k0 = 0; k0 < D; k0 += 16) {
    xs[ti][tj] = x[(size_t)(brow + ti) * D + k0 + tj];
    ys[ti][tj] = y[(size_t)(bcol + ti) * D + k0 + tj];
    __syncthreads();
    #pragma unroll
    for (int kk = 0; kk < 16; ++kk) {
      float xv = xs[ti][kk], yv = ys[tj][kk];
      dacc += xv * yv;
      xacc += xv * xv;
      yacc += yv * yv;
    }
    __syncthreads();
  }
  float gamma = gptr[0];
  float d2 = fmaxf(xacc + yacc - 2.f * dacc, 0.f);
  out[(size_t)(brow + ti) * M + (bcol + tj)] = __expf(-gamma * d2);
}

// ---------------------------------------------------------------------------
extern "C" void kernel_launch(void* const* d_in, const int* in_sizes, int n_in,
                              void* d_out, int out_size, void* d_ws,
                              size_t ws_size, hipStream_t stream) {
  const float* x = (const float*)d_in[0];
  const float* y = (const float*)d_in[1];
  const float* g = (const float*)d_in[2];
  float* out = (float*)d_out;

  const int D = 512;
  const int N = in_sizes[0] / D;
  const int M = in_sizes[1] / D;

  size_t need = (size_t)(N + M) * D * sizeof(u16) + (size_t)(N + M) * sizeof(float);
  bool shapes_ok = (N % BM == 0) && (M % (BN * NTILE) == 0) && (D % BK == 0) &&
                   ((D / BK) >= 2);

  if (ws_size >= need && shapes_ok) {
    u16* xb = (u16*)d_ws;
    u16* yb = xb + (size_t)N * D;
    float* xsq = (float*)(yb + (size_t)M * D);
    float* ysq = xsq + N;

    rbf_prep<<<N + M, 128, 0, stream>>>(x, y, xb, yb, xsq, ysq, N, M, D);
    int nwg = (N / BM) * (M / (BN * NTILE));
    rbf_gemm<<<nwg, 256, 0, stream>>>(xb, yb, xsq, ysq, g, out, N, M, D);
  } else {
    rbf_naive<<<(N / 16) * (M / 16), 256, 0, stream>>>(x, y, g, out, N, M, D);
  }
}

// Round 13
// 112.453 us; speedup vs baseline: 2.3213x; 1.0430x over previous
//
#include <hip/hip_runtime.h>
#include <hip/hip_bf16.h>

typedef unsigned short u16;
typedef __attribute__((ext_vector_type(8))) short bf16x8;
typedef __attribute__((ext_vector_type(4))) float f32x4;

typedef const __attribute__((address_space(1))) void gvoid_t;
typedef __attribute__((address_space(3))) void lvoid_t;

__device__ __forceinline__ void gload_lds16(const void* g, void* l) {
  __builtin_amdgcn_global_load_lds((gvoid_t*)g, (lvoid_t*)l, 16, 0, 0);
}

__device__ __forceinline__ u16 f2bf(float f) {
  union { float f; unsigned u; } a;
  a.f = f;
  unsigned r = (a.u + 0x7FFFu + ((a.u >> 16) & 1u)) >> 16;  // RN-even
  return (u16)r;
}

// ---------------------------------------------------------------------------
// Prep: fp32 -> bf16 copies of x and y, plus per-row sum of squares.
// ---------------------------------------------------------------------------
__global__ __launch_bounds__(128) void rbf_prep(
    const float* __restrict__ x, const float* __restrict__ y,
    u16* __restrict__ xb, u16* __restrict__ yb,
    float* __restrict__ xsq, float* __restrict__ ysq,
    int N, int M, int D) {
  int row = blockIdx.x;
  const float* src;
  u16* dst;
  float* sq;
  if (row < N) {
    src = x + (size_t)row * D;
    dst = xb + (size_t)row * D;
    sq = xsq + row;
  } else {
    int r = row - N;
    src = y + (size_t)r * D;
    dst = yb + (size_t)r * D;
    sq = ysq + r;
  }
  int t = threadIdx.x;
  float4 v = reinterpret_cast<const float4*>(src)[t];
  float s = v.x * v.x + v.y * v.y + v.z * v.z + v.w * v.w;
  ushort4 o;
  o.x = f2bf(v.x);
  o.y = f2bf(v.y);
  o.z = f2bf(v.z);
  o.w = f2bf(v.w);
  reinterpret_cast<ushort4*>(dst)[t] = o;
  #pragma unroll
  for (int off = 32; off > 0; off >>= 1) s += __shfl_down(s, off, 64);
  __shared__ float red[2];
  if ((t & 63) == 0) red[t >> 6] = s;
  __syncthreads();
  if (t == 0) sq[0] = red[0] + red[1];
}

// ---------------------------------------------------------------------------
// R13 = R5 (verified best, 112.7 us) with two strictly-safe micro-deltas:
//  (1) s_setprio REMOVED from the K-loop: m190 measured setprio ~0/negative
//      on 2-phase GEMM structures (T5 pays only on 8-phase role-split).
//  (2) epilogue norm loads (xsq/ysq) HOISTED above the K-loop: absorbs the
//      up-to-900cy epilogue-entry load latency into the idle prologue.
// Everything else byte-identical to R5: 128x128 tile, BK=64, 4 waves
// (2Mx2N), LDS 64 KiB dbuf -> 2 blocks/CU; 3-bit chunk^=(row&7) swizzle
// both sides; counted vmcnt(8) 2-iteration lookahead; 2 barriers/K-tile;
// swapped MFMA operands -> D[j][i] -> float4 stores; column-band supertile;
// exp2-fused epilogue.
// ---------------------------------------------------------------------------
#define BM 128
#define BN 128
#define BK 64

__global__ __launch_bounds__(256, 2) void rbf_gemm(
    const u16* __restrict__ xb, const u16* __restrict__ yb,
    const float* __restrict__ xsq, const float* __restrict__ ysq,
    const float* __restrict__ gptr, float* __restrict__ out,
    int N, int M, int D) {
  __shared__ u16 lds[2][2][BM * BK];  // 64 KiB

  int bid = blockIdx.x;
  int nbr = N / BM, nbc = M / BN;
  int trow, tcol;
  if (nbr == 64 && nbc == 64) {
    // XCD x owns tile-columns x*8..x*8+7, walked in 8x8-tile regions
    // (column-major inside a region): panels stay L2-resident per XCD.
    int xcd = bid & 7;
    int s = bid >> 3;        // 0..511
    int gr = s >> 6;         // region row 0..7
    int q = s & 63;          // within-region, column-major
    trow = gr * 8 + (q & 7);
    tcol = xcd * 8 + (q >> 3);
  } else {
    int cpx = gridDim.x >> 3;
    int swz = (bid & 7) * cpx + (bid >> 3);
    trow = swz / nbc;
    tcol = swz % nbc;
  }
  int brow = trow * BM;
  int bcol = tcol * BN;

  int tid = threadIdx.x;
  int w = tid >> 6;       // wave 0..3
  int lane = tid & 63;
  int wm = w >> 1;        // 0..1 row half (64 rows)
  int wn = w & 1;         // 0..1 col half (64 cols)
  int fr = lane & 15;
  int fq = lane >> 4;

  // --- staging: wave w stages rows w*32..w*32+31 of A and B tiles ---
  int srow = lane >> 3;                        // 0..7
  int scol = ((lane & 7) ^ srow) * 8;          // inverse-swizzled source col
  const u16* xsrc = xb + (size_t)(brow + w * 32 + srow) * D + scol;
  const u16* ysrc = yb + (size_t)(bcol + w * 32 + srow) * D + scol;
  int sdst = w * 2048;  // 32 rows * 64 elems

  // --- fragment read offsets: chunk ^= (row&7) ---
  int cxor = (fr & 7) * 8;
  int colx0 = (fq * 8) ^ cxor;        // kk=0
  int colx1 = (32 + fq * 8) ^ cxor;   // kk=1
  int arow0 = (wm * 64 + fr) * 64;
  int brow0 = (wn * 64 + fr) * 64;

  // --- hoisted epilogue constants & norm loads (latency-free in prologue) ---
  float gl2 = gptr[0] * 1.44269504088896f;  // gamma * log2(e)
  float m2gl2 = 2.0f * gl2;
  float gxs[4];
  float4 gys[4];
  #pragma unroll
  for (int m = 0; m < 4; ++m)
    gxs[m] = gl2 * xsq[brow + wm * 64 + m * 16 + fr];
  #pragma unroll
  for (int n = 0; n < 4; ++n) {
    float4 t4 = *reinterpret_cast<const float4*>(
        &ysq[bcol + wn * 64 + n * 16 + fq * 4]);
    gys[n].x = gl2 * t4.x;
    gys[n].y = gl2 * t4.y;
    gys[n].z = gl2 * t4.z;
    gys[n].w = gl2 * t4.w;
  }

  f32x4 acc[4][4];
  #pragma unroll
  for (int m = 0; m < 4; ++m)
    #pragma unroll
    for (int n = 0; n < 4; ++n)
      acc[m][n] = (f32x4){0.f, 0.f, 0.f, 0.f};

  auto stage = [&](int kt, int b) {
    const u16* xs = xsrc + kt * 64;
    const u16* ys = ysrc + kt * 64;
    u16* la = &lds[b][0][sdst];
    u16* lb = &lds[b][1][sdst];
    #pragma unroll
    for (int i = 0; i < 4; ++i)
      gload_lds16(xs + (size_t)i * 8 * D, la + i * 512);
    #pragma unroll
    for (int i = 0; i < 4; ++i)
      gload_lds16(ys + (size_t)i * 8 * D, lb + i * 512);
  };

  int nkt = D >> 6;  // 8
  stage(0, 0);
  stage(1, 1);
  for (int t = 0; t < nkt; ++t) {
    int b = t & 1;
    // my 8 loads of tile t landed (8 of tile t+1 stay in flight)
    if (t + 1 < nkt)
      asm volatile("s_waitcnt vmcnt(8)" ::: "memory");
    else
      asm volatile("s_waitcnt vmcnt(0)" ::: "memory");
    __builtin_amdgcn_sched_barrier(0);
    __builtin_amdgcn_s_barrier();  // all waves' tile-t data visible
    __builtin_amdgcn_sched_barrier(0);

    const u16* A = &lds[b][0][0];
    const u16* B = &lds[b][1][0];
    bf16x8 af[4][2], bf[4][2];
    #pragma unroll
    for (int m = 0; m < 4; ++m) {
      af[m][0] = *(const bf16x8*)&A[arow0 + m * 1024 + colx0];
      af[m][1] = *(const bf16x8*)&A[arow0 + m * 1024 + colx1];
    }
    #pragma unroll
    for (int n = 0; n < 4; ++n) {
      bf[n][0] = *(const bf16x8*)&B[brow0 + n * 1024 + colx0];
      bf[n][1] = *(const bf16x8*)&B[brow0 + n * 1024 + colx1];
    }

    // Swapped operands: D[j][i], j = fq*4 + r, i = fr. (no setprio: m190)
    #pragma unroll
    for (int m = 0; m < 4; ++m)
      #pragma unroll
      for (int n = 0; n < 4; ++n) {
        acc[m][n] = __builtin_amdgcn_mfma_f32_16x16x32_bf16(
            bf[n][0], af[m][0], acc[m][n], 0, 0, 0);
        acc[m][n] = __builtin_amdgcn_mfma_f32_16x16x32_bf16(
            bf[n][1], af[m][1], acc[m][n], 0, 0, 0);
      }

    // my ds_reads of buf b done before anyone re-stages into it
    asm volatile("s_waitcnt lgkmcnt(0)" ::: "memory");
    __builtin_amdgcn_sched_barrier(0);
    __builtin_amdgcn_s_barrier();
    __builtin_amdgcn_sched_barrier(0);
    if (t + 2 < nkt) stage(t + 2, b);
  }

  // Epilogue: out = exp2(2*gl2*acc - gl2*|x|^2 - gl2*|y|^2), clamped <= 2^0.
  #pragma unroll
  for (int m = 0; m < 4; ++m) {
    int i = brow + wm * 64 + m * 16 + fr;
    size_t ro = (size_t)i * M;
    #pragma unroll
    for (int n = 0; n < 4; ++n) {
      int jb = bcol + wn * 64 + n * 16 + fq * 4;
      float4 e;
      e.x = exp2f(fminf(fmaf(m2gl2, acc[m][n][0], -(gxs[m] + gys[n].x)), 0.f));
      e.y = exp2f(fminf(fmaf(m2gl2, acc[m][n][1], -(gxs[m] + gys[n].y)), 0.f));
      e.z = exp2f(fminf(fmaf(m2gl2, acc[m][n][2], -(gxs[m] + gys[n].z)), 0.f));
      e.w = exp2f(fminf(fmaf(m2gl2, acc[m][n][3], -(gxs[m] + gys[n].w)), 0.f));
      *reinterpret_cast<float4*>(&out[ro + jb]) = e;
    }
  }
}

// ---------------------------------------------------------------------------
// Fallback: fp32 LDS-tiled, slow but correct for odd shapes.
// ---------------------------------------------------------------------------
__global__ __launch_bounds__(256) void rbf_naive(
    const float* __restrict__ x, const float* __restrict__ y,
    const float* __restrict__ gptr, float* __restrict__ out,
    int N, int M, int D) {
  __shared__ float xs[16][17];
  __shared__ float ys[16][17];
  int nbn = M / 16;
  int brow = (blockIdx.x / nbn) * 16;
  int bcol = (blockIdx.x % nbn) * 16;
  int ti = threadIdx.x >> 4, tj = threadIdx.x & 15;
  float dacc = 0.f, xacc = 0.f, yacc = 0.f;
  for (int k0 = 0; k0 < D; k0 += 16) {
    xs[ti][tj] = x[(size_t)(brow + ti) * D + k0 + tj];
    ys[ti][tj] = y[(size_t)(bcol + ti) * D + k0 + tj];
    __syncthreads();
    #pragma unroll
    for (int kk = 0; kk < 16; ++kk) {
      float xv = xs[ti][kk], yv = ys[tj][kk];
      dacc += xv * yv;
      xacc += xv * xv;
      yacc += yv * yv;
    }
    __syncthreads();
  }
  float gamma = gptr[0];
  float d2 = fmaxf(xacc + yacc - 2.f * dacc, 0.f);
  out[(size_t)(brow + ti) * M + (bcol + tj)] = __expf(-gamma * d2);
}

// ---------------------------------------------------------------------------
extern "C" void kernel_launch(void* const* d_in, const int* in_sizes, int n_in,
                              void* d_out, int out_size, void* d_ws,
                              size_t ws_size, hipStream_t stream) {
  const float* x = (const float*)d_in[0];
  const float* y = (const float*)d_in[1];
  const float* g = (const float*)d_in[2];
  float* out = (float*)d_out;

  const int D = 512;
  const int N = in_sizes[0] / D;
  const int M = in_sizes[1] / D;

  size_t need = (size_t)(N + M) * D * sizeof(u16) + (size_t)(N + M) * sizeof(float);
  bool shapes_ok = (N % BM == 0) && (M % BN == 0) && (D % BK == 0) && (D / BK >= 2);

  if (ws_size >= need && shapes_ok) {
    u16* xb = (u16*)d_ws;
    u16* yb = xb + (size_t)N * D;
    float* xsq = (float*)(yb + (size_t)M * D);
    float* ysq = xsq + N;

    rbf_prep<<<N + M, 128, 0, stream>>>(x, y, xb, yb, xsq, ysq, N, M, D);
    int nwg = (N / BM) * (M / BN);
    rbf_gemm<<<nwg, 256, 0, stream>>>(xb, yb, xsq, ysq, g, out, N, M, D);
  } else {
    rbf_naive<<<(N / 16) * (M / 16), 256, 0, stream>>>(x, y, g, out, N, M, D);
  }
}